// Round 10
// baseline (494.113 us; speedup 1.0000x reference)
//
#include <hip/hip_runtime.h>
#include <cmath>
#include <cstdint>
#include <cstddef>

#define NT 17
#define NP 45
#define CH 8
#define HS 528   // hist column stride (bytes): 16|528 for staging, 8|528 for
                 // u64 stores, dword-stride 132 -> 4-way LDS bank alias (ok)
// B=64, S=512, H=768

__device__ __forceinline__ float rlane(float v, int k) {
    return __int_as_float(__builtin_amdgcn_readlane(__float_as_int(v), k));
}

// Broadcast lane k's value to all lanes via the LDS crossbar (ds_bpermute).
__device__ __forceinline__ float bperm(float v, int k) {
    return __int_as_float(__builtin_amdgcn_ds_bpermute(k * 4, __float_as_int(v)));
}

// 16B async global->LDS DMA (no VGPR round-trip, no ds_write instruction).
__device__ __forceinline__ void gload16(const float* g, float* l) {
    __builtin_amdgcn_global_load_lds(
        (const __attribute__((address_space(1))) void*)g,
        (__attribute__((address_space(3))) void*)l, 16, 0, 0);
}

// ---------------------------------------------------------------------------
// Kernel 0: pack W into Wpk[768][64] (17 tag cols | 45 pos cols | 2 zero pad)
// ---------------------------------------------------------------------------
__global__ __launch_bounds__(256) void pack_w(
    const float* __restrict__ Wt, const float* __restrict__ Wp,
    float* __restrict__ Wpk)
{
    int i = blockIdx.x * 256 + threadIdx.x;
    if (i >= 768 * 64) return;
    int k = i >> 6, c = i & 63;
    float v = 0.f;
    if (c < NT) v = Wt[k * NT + c];
    else if (c < NT + NP) v = Wp[k * NP + (c - NT)];
    Wpk[i] = v;
}

// ---------------------------------------------------------------------------
// Kernel 1: logits = hidden @ [W_tag | W_pos] + bias   (f32 vector GEMM)
// DMA-staged tiles, source-side XOR swizzle on As, zero LDS staging instrs,
// conflict-free reads. Accumulation per output is the identical strictly-
// ascending-k fmaf chain with bias added last -> logits bitwise unchanged.
// ---------------------------------------------------------------------------
__global__ __launch_bounds__(256) void gemm_logits(
    const float* __restrict__ hidden, const float* __restrict__ Wpk,
    const float* __restrict__ bt, const float* __restrict__ bp,
    float* __restrict__ tagL, float* __restrict__ posL)
{
    __shared__ __align__(16) float As[64 * 32];
    __shared__ __align__(16) float Bs[32 * 64];
    const int tid = threadIdx.x;
    const int rg = tid >> 4;
    const int cg = tid & 15;
    const int srg = rg & 7;
    const int row0 = blockIdx.x * 64;

    float acc[4][4];
#pragma unroll
    for (int a = 0; a < 4; ++a)
#pragma unroll
        for (int b = 0; b < 4; ++b) acc[a][b] = 0.f;

    const int arow = tid >> 3;
    const int aq   = tid & 7;
    const int bk   = tid >> 4;
    const int bc4  = tid & 15;

#pragma unroll 1
    for (int kc = 0; kc < 768; kc += 32) {
        {
            int r0 = arow;
            int s0 = (r0 >> 2) & 7;
            gload16(hidden + (size_t)(row0 + r0) * 768 + kc + ((aq ^ s0) << 2),
                    As + r0 * 32 + aq * 4);
            int r1 = 32 + arow;
            int s1 = (r1 >> 2) & 7;
            gload16(hidden + (size_t)(row0 + r1) * 768 + kc + ((aq ^ s1) << 2),
                    As + r1 * 32 + aq * 4);
            gload16(Wpk + (size_t)(kc + bk) * 64 + bc4 * 4,
                    Bs + bk * 64 + bc4 * 4);
            gload16(Wpk + (size_t)(kc + 16 + bk) * 64 + bc4 * 4,
                    Bs + (16 + bk) * 64 + bc4 * 4);
        }
        __syncthreads();
#pragma unroll
        for (int k4 = 0; k4 < 8; ++k4) {
            const int qb = ((k4 ^ srg) << 2);
            float a_[4][4], b_[4][4];
#pragma unroll
            for (int jr = 0; jr < 4; ++jr) {
                float4 t = *(const float4*)(As + (rg * 4 + jr) * 32 + qb);
                a_[jr][0] = t.x; a_[jr][1] = t.y; a_[jr][2] = t.z; a_[jr][3] = t.w;
            }
#pragma unroll
            for (int kk = 0; kk < 4; ++kk) {
                float4 t = *(const float4*)(Bs + (k4 * 4 + kk) * 64 + cg * 4);
                b_[kk][0] = t.x; b_[kk][1] = t.y; b_[kk][2] = t.z; b_[kk][3] = t.w;
            }
#pragma unroll
            for (int kk = 0; kk < 4; ++kk)
#pragma unroll
                for (int jr = 0; jr < 4; ++jr)
#pragma unroll
                    for (int jc = 0; jc < 4; ++jc)
                        acc[jr][jc] = fmaf(a_[jr][kk], b_[kk][jc], acc[jr][jc]);
        }
        __syncthreads();
    }
#pragma unroll
    for (int jr = 0; jr < 4; ++jr) {
        size_t r = (size_t)row0 + rg * 4 + jr;
#pragma unroll
        for (int jc = 0; jc < 4; ++jc) {
            int c = cg * 4 + jc;
            if (c < NT) tagL[r * NT + c] = acc[jr][jc] + bt[c];
            else if (c < NT + NP) posL[r * NP + (c - NT)] = acc[jr][jc] + bp[c - NT];
        }
    }
}

// ---------------------------------------------------------------------------
// Kernel 2: the four CRF scans. One wave per (b, role); 256 blocks x 64 thr.
// NLL path unchanged (bitwise identical). Round-9: vit_fwd FUSES the
// backpointer computation into the forward scan: at step t the broadcast
// bv[] IS score[t-1], so argmax_i(bv[i]+Tcol[i]) with a strict-> first-max
// chain reproduces the old hist_kernel EXACTLY (4 contiguous index chains +
// left-priority combine = ascending strict-> scan). The per-step score
// store is GONE (scan kernel = max over roles; only vit stored in-loop,
// and stores share vmcnt with the en[] prefetch -> per-chunk store drains
// were the stall candidate). Backpointer bytes are packed 8/chunk into ONE
// u64 store (transposed hist: histX[b][col][t], stride HS). sc recurrence
// is untouched -> bitwise-identical scores, den/num, and paths.
// ---------------------------------------------------------------------------
template <int T, int PAD>
__device__ void nll_scan(int b,
    const float* __restrict__ logits, const int* __restrict__ mask,
    const int* __restrict__ targ, const float* __restrict__ start,
    const float* __restrict__ trans, const float* __restrict__ endv,
    float* __restrict__ den, float* __restrict__ num)
{
    const int lane = threadIdx.x;
    const int jj = (lane < T) ? lane : (T - 1);
    float Ecol[PAD];
#pragma unroll
    for (int i = 0; i < PAD; ++i) Ecol[i] = (i < T) ? __expf(trans[i * T + jj]) : 0.f;
    const float esjj = __expf(start[jj]);
    const float* eptr = logits + (size_t)b * 512 * T + jj;
    const int* mptr = mask + b * 512;

    float eb[CH], en[CH], fb[CH];
    int mb, mn = 0;
#pragma unroll
    for (int k = 0; k < CH; ++k) { eb[k] = eptr[k * T]; en[k] = 0.f; }
    mb = mptr[lane & (CH - 1)];

    float a = 0.f;
    int excorr = 0;
    for (int c = 0; c < 64; ++c) {
        unsigned long long kb = __ballot(mb > 0);
        if (c < 63) {
            const float* ep2 = eptr + (c + 1) * CH * T;
#pragma unroll
            for (int k = 0; k < CH; ++k) en[k] = ep2[k * T];
            mn = mptr[(c + 1) * CH + (lane & (CH - 1))];
        }
#pragma unroll
        for (int k = 0; k < CH; ++k) fb[k] = __expf(eb[k]);   // off-chain
#pragma unroll
        for (int s = 0; s < CH; ++s) {
            float bv[PAD];
#pragma unroll
            for (int i = 0; i < PAD; ++i) bv[i] = bperm(a, i);
            float d0 = 0.f, d1 = 0.f, d2 = 0.f, d3 = 0.f;
#pragma unroll
            for (int q = 0; q < PAD / 4; ++q) {
                d0 = fmaf(bv[4 * q + 0], Ecol[4 * q + 0], d0);
                d1 = fmaf(bv[4 * q + 1], Ecol[4 * q + 1], d1);
                d2 = fmaf(bv[4 * q + 2], Ecol[4 * q + 2], d2);
                d3 = fmaf(bv[4 * q + 3], Ecol[4 * q + 3], d3);
            }
            float cand = ((d0 + d1) + (d2 + d3)) * fb[s];
            bool keep = (kb >> s) & 1ULL;
            bool first = (c == 0) && (s == 0);
            a = first ? (esjj * fb[0]) : (keep ? cand : a);
        }
        // exact power-of-2 rescale; wave-uniform max via readlane tree.
        float mv0 = rlane(a, 0), mv1 = rlane(a, 1);
        float mv2 = rlane(a, 2), mv3 = rlane(a, 3);
#pragma unroll
        for (int i = 4; i < T; i += 4) {
            mv0 = fmaxf(mv0, rlane(a, i + 0));
            mv1 = fmaxf(mv1, rlane(a, i + 1));
            mv2 = fmaxf(mv2, rlane(a, i + 2));
            mv3 = fmaxf(mv3, rlane(a, i + 3));
        }
        float m = fmaxf(fmaxf(mv0, mv1), fmaxf(mv2, mv3));
        int ex;
        (void)frexpf(m, &ex);
        a *= ldexpf(1.0f, -ex);
        excorr += ex;
#pragma unroll
        for (int k = 0; k < CH; ++k) eb[k] = en[k];
        mb = mn;
    }
    float term = (lane < T) ? a * __expf(endv[lane]) : 0.f;
#pragma unroll
    for (int o = 32; o; o >>= 1) term += __shfl_xor(term, o);
    if (lane == 0) den[b] = __logf(term) + (float)excorr * 0.69314718056f;

    float part = 0.f; int Lc = 0;
    for (int t = lane; t < 512; t += 64) {
        int mt = mask[b * 512 + t];
        Lc += (mt > 0);
        if (t >= 1 && mt > 0) {
            int tg = targ[b * 512 + t];
            int pg = targ[b * 512 + t - 1];
            part += trans[pg * T + tg] + logits[((size_t)b * 512 + t) * T + tg];
        }
    }
#pragma unroll
    for (int o = 32; o; o >>= 1) { part += __shfl_xor(part, o); Lc += __shfl_xor(Lc, o); }
    if (lane == 0) {
        int t0g = targ[b * 512];
        num[b] = start[t0g] + logits[(size_t)b * 512 * T + t0g]
               + part + endv[targ[b * 512 + Lc - 1]];
    }
}

// Viterbi forward with FUSED backpointer emission. Backpointers for row
// t-1 are computed from the same bv[] broadcast the recurrence uses
// (bv == score[t-1]); first-max tie-break = strict >, ascending contiguous
// chains + left-priority combine -> identical to old hist_block. 8 bytes
// packed per chunk -> one u64 store per chunk per lane (col-major histX).
// Only the FINAL score row is stored (scoreFin), for backtrace's argmax.
template <int T, int PAD>
__device__ void vit_fwd(int b,
    const float* __restrict__ logits, const int* __restrict__ mask,
    const float* __restrict__ start, const float* __restrict__ trans,
    float* __restrict__ scoreFin, unsigned char* __restrict__ histX)
{
    constexpr int L = PAD / 4;
    const int lane = threadIdx.x;
    const int jj = (lane < T) ? lane : (T - 1);
    float Tcol[PAD];
#pragma unroll
    for (int i = 0; i < PAD; ++i) Tcol[i] = (i < T) ? trans[i * T + jj] : -1e30f;
    const float sjj = start[jj];
    const float* eptr = logits + (size_t)b * 512 * T + jj;
    const int* mptr = mask + b * 512;
    unsigned char* hbase = histX + ((size_t)b * T + lane) * HS;

    float eb[CH], en[CH];
    int mb, mn = 0;
#pragma unroll
    for (int k = 0; k < CH; ++k) { eb[k] = eptr[k * T]; en[k] = 0.f; }
    mb = mptr[lane & (CH - 1)];

    float sc = 0.f;
    unsigned int plo = 0, phi = 0;
    for (int c = 0; c < 64; ++c) {
        unsigned long long kb = __ballot(mb > 0);
        if (c < 63) {
            const float* ep2 = eptr + (c + 1) * CH * T;
#pragma unroll
            for (int k = 0; k < CH; ++k) en[k] = ep2[k * T];
            mn = mptr[(c + 1) * CH + (lane & (CH - 1))];
        }
#pragma unroll
        for (int s = 0; s < CH; ++s) {
            float bv[PAD];
#pragma unroll
            for (int i = 0; i < PAD; ++i) bv[i] = bperm(sc, i);
            float cnd[PAD];
#pragma unroll
            for (int i = 0; i < PAD; ++i) cnd[i] = bv[i] + Tcol[i];
            // max for the recurrence: ORIGINAL pairwise order (exact value)
            float m = -1e30f;
#pragma unroll
            for (int q = 0; q < PAD / 4; ++q) {
                m = fmaxf(m, fmaxf(cnd[4 * q + 0], cnd[4 * q + 1]));
                m = fmaxf(m, fmaxf(cnd[4 * q + 2], cnd[4 * q + 3]));
            }
            // first-index argmax (== hist_block's ascending strict-> chain):
            // 4 CONTIGUOUS chains, combined left-first. Off the critical path.
            float mc0 = cnd[0];         int ac0 = 0;
            float mc1 = cnd[L];         int ac1 = L;
            float mc2 = cnd[2 * L];     int ac2 = 2 * L;
            float mc3 = cnd[3 * L];     int ac3 = 3 * L;
#pragma unroll
            for (int i = 1; i < L; ++i) {
                float c0 = cnd[i];          bool g0 = c0 > mc0;
                mc0 = g0 ? c0 : mc0;        ac0 = g0 ? i : ac0;
                float c1 = cnd[L + i];      bool g1 = c1 > mc1;
                mc1 = g1 ? c1 : mc1;        ac1 = g1 ? (L + i) : ac1;
                float c2 = cnd[2 * L + i];  bool g2 = c2 > mc2;
                mc2 = g2 ? c2 : mc2;        ac2 = g2 ? (2 * L + i) : ac2;
                float c3 = cnd[3 * L + i];  bool g3 = c3 > mc3;
                mc3 = g3 ? c3 : mc3;        ac3 = g3 ? (3 * L + i) : ac3;
            }
            float mx = mc0; int am = ac0;
            { bool g = mc1 > mx; mx = g ? mc1 : mx; am = g ? ac1 : am; }
            { bool g = mc2 > mx; mx = g ? mc2 : mx; am = g ? ac2 : am; }
            { bool g = mc3 > mx; mx = g ? mc3 : mx; am = g ? ac3 : am; }

            bool keep = (kb >> s) & 1ULL;
            bool first = (c == 0) && (s == 0);
            float nxt = m + eb[s];
            sc = first ? (sjj + eb[0]) : (keep ? nxt : sc);
            int hv = keep ? am : jj;            // identity when masked
            // pack byte for row tt-1 (tt = c*8+s); store 8 rows per chunk
            if (s == 0) {
                if (c > 0) {                     // row 8c-1 -> byte 7; flush
                    phi |= (unsigned)hv << 24;
                    if (lane < T)
                        *(unsigned long long*)(hbase + (c * CH - 8)) =
                            ((unsigned long long)phi << 32) | plo;
                    plo = 0; phi = 0;
                }
            } else if (s <= 4) {
                plo |= (unsigned)hv << (8 * (s - 1));
            } else {
                phi |= (unsigned)hv << (8 * (s - 5));
            }
        }
#pragma unroll
        for (int k = 0; k < CH; ++k) eb[k] = en[k];
        mb = mn;
    }
    if (lane < T) {
        // flush rows 504..510 (byte 7 = unused row 511, harmless zero)
        *(unsigned long long*)(hbase + 504) =
            ((unsigned long long)phi << 32) | plo;
        scoreFin[b * 64 + lane] = sc;
    }
}

__global__ __launch_bounds__(64, 1) void scan_kernel(
    const float* tagL, const float* posL, const int* mask,
    const int* tgT, const int* tgP,
    const float* startT, const float* transT, const float* endT,
    const float* startP, const float* transP, const float* endP,
    float* scFT, float* scFP,
    unsigned char* histXT, unsigned char* histXP,
    float* denT, float* denP, float* numT, float* numP)
{
    int bid = blockIdx.x;
    if (bid < 64)
        vit_fwd<NP, 48>(bid, posL, mask, startP, transP, scFP, histXP);
    else if (bid < 128)
        nll_scan<NP, 48>(bid - 64, posL, mask, tgP, startP, transP, endP, denP, numP);
    else if (bid < 192)
        vit_fwd<NT, 20>(bid - 128, tagL, mask, startT, transT, scFT, histXT);
    else
        nll_scan<NT, 20>(bid - 192, tagL, mask, tgT, startT, transT, endT, denT, numT);
}

// ---------------------------------------------------------------------------
// Kernel 3: backtrace with pointer-jump composition. hist is COLUMN-major
// (histX[b][col][t], stride HS): H(r,i) = h[i*HS + r]. Block 128 computes
// the losses (merged finalize).
// ---------------------------------------------------------------------------
template <int T>
__device__ void backtrace(int b, const float* __restrict__ scoreFin,
    const unsigned char* __restrict__ histX, const float* __restrict__ endv,
    float* __restrict__ outp, unsigned char* sh)
{
    unsigned char* h  = sh;                    // [T][HS] col-major backptrs
    unsigned char* g2 = sh + HS * T;           // [510][T] row-major
    unsigned char* g4 = sh + (HS + 512) * T;   // 127 rows
    unsigned char* g8 = sh + (HS + 640) * T;   // 63 rows
    unsigned char* pr = sh + (HS + 704) * T;   // 512
    const int lane = threadIdx.x;

    {   // stage histX b-slab (T*HS bytes, contiguous, 16B multiple)
        const int4* src = (const int4*)(histX + (size_t)b * T * HS);
        int4* dst = (int4*)h;
        int n16 = (T * HS) / 16;
        for (int i = lane; i < n16; i += 64) dst[i] = src[i];
    }
    __syncthreads();
    // g2[r][i] = H(r, H(r+1, i))  (maps cur at t=r+2 -> t=r)
    for (int idx = lane; idx < 510 * T; idx += 64) {
        int r = idx / T, i = idx - r * T;
        g2[idx] = h[(int)h[i * HS + (r + 1)] * HS + r];
    }
    __syncthreads();
    // g4 rows r = 3+4*a4: g4[a4][i] = g2[r][ g2[r+2][i] ]
    for (int idx = lane; idx < 127 * T; idx += 64) {
        int a4 = idx / T, i = idx - a4 * T;
        int r = 3 + 4 * a4;
        g4[idx] = g2[r * T + g2[(r + 2) * T + i]];
    }
    __syncthreads();
    // g8 rows r = 503-8a: g8[a][i] = g4row(r)[ g4row(r+4)[i] ]
    for (int idx = lane; idx < 63 * T; idx += 64) {
        int a = idx / T, i = idx - a * T;
        int r = 503 - 8 * a;
        int a4lo = (r - 3) >> 2, a4hi = (r + 1) >> 2;
        g8[idx] = g4[a4lo * T + g4[a4hi * T + i]];
    }
    // last = first-index argmax(scoreFin + end)
    float v = (lane < T) ? (scoreFin[b * 64 + lane] + endv[lane]) : -1e30f;
    float mx = v;
#pragma unroll
    for (int o = 32; o; o >>= 1) mx = fmaxf(mx, __shfl_xor(mx, o));
    unsigned long long bal = __ballot(v == mx);
    int cur = __ffsll(bal) - 1;
    __syncthreads();
    // phase A: serial anchor chain, 63 dependent LDS reads
    int myCur = 0;
    for (int a = 0; a < 64; ++a) {
        if (lane == a) myCur = cur;
        if (a < 63) cur = g8[a * T + cur];
    }
    // phase B: each lane fills its 8-step segment
    {
        int ta = 511 - 8 * lane;
        int j = myCur;
        pr[ta] = (unsigned char)j;
        int rlo = (lane == 63) ? 0 : (ta - 7);
        for (int r = ta - 1; r >= rlo; --r) {
            j = h[j * HS + r];
            pr[r] = (unsigned char)j;
        }
    }
    __syncthreads();
    for (int k = lane; k < 512; k += 64)
        outp[(size_t)b * 512 + k] = (float)pr[k];
}

__global__ __launch_bounds__(64, 1) void backtrace_kernel(
    const float* scFT, const float* scFP,
    const unsigned char* histXT, const unsigned char* histXP,
    const float* endT, const float* endP,
    const float* numT, const float* denT,
    const float* numP, const float* denP, float* out)
{
    __shared__ __align__(16) unsigned char sh[(HS + 704) * NP + 512];
    int blk = blockIdx.x;
    if (blk < 64) backtrace<NP>(blk, scFP, histXP, endP, out + 32768, sh);
    else if (blk < 128) backtrace<NT>(blk - 64, scFT, histXT, endT, out, sh);
    else {
        // merged finalize: losses = -mean(num - den)
        int lane = threadIdx.x;
        float dT = numT[lane] - denT[lane];
        float dP = numP[lane] - denP[lane];
#pragma unroll
        for (int o = 32; o; o >>= 1) { dT += __shfl_xor(dT, o); dP += __shfl_xor(dP, o); }
        if (lane == 0) {
            out[65536] = -dT / 64.f;
            out[65537] = -dP / 64.f;
        }
    }
}

// ---------------------------------------------------------------------------
extern "C" void kernel_launch(void* const* d_in, const int* in_sizes, int n_in,
                              void* d_out, int out_size, void* d_ws, size_t ws_size,
                              hipStream_t stream)
{
    const float* hidden = (const float*)d_in[0];
    const int*   mask   = (const int*)d_in[1];
    const int*   tgT    = (const int*)d_in[2];
    const int*   tgP    = (const int*)d_in[3];
    const float* Wt     = (const float*)d_in[4];
    const float* bt     = (const float*)d_in[5];
    const float* Wp     = (const float*)d_in[6];
    const float* bp     = (const float*)d_in[7];
    const float* startT = (const float*)d_in[8];
    const float* transT = (const float*)d_in[9];
    const float* endT   = (const float*)d_in[10];
    const float* startP = (const float*)d_in[11];
    const float* transP = (const float*)d_in[12];
    const float* endP   = (const float*)d_in[13];

    float* ws   = (float*)d_ws;
    float* tagL = ws;                              // 557056 f
    float* posL = tagL + 557056;                   // 1474560 f
    float* Wpk  = posL + 1474560;                  // 49152 f
    float* denT = Wpk + 49152;                     // 64
    float* denP = denT + 64;
    float* numT = denP + 64;
    float* numP = numT + 64;
    float* scFT = numP + 64;                       // 4096 f
    float* scFP = scFT + 4096;                     // 4096 f
    unsigned char* histXT = (unsigned char*)(scFP + 4096);   // 64*NT*HS B
    unsigned char* histXP = histXT + (size_t)64 * NT * HS;   // 64*NP*HS B
    float* out = (float*)d_out;

    pack_w<<<192, 256, 0, stream>>>(Wt, Wp, Wpk);
    gemm_logits<<<512, 256, 0, stream>>>(hidden, Wpk, bt, bp, tagL, posL);
    scan_kernel<<<256, 64, 0, stream>>>(tagL, posL, mask, tgT, tgP,
        startT, transT, endT, startP, transP, endP,
        scFT, scFP, histXT, histXP, denT, denP, numT, numP);
    backtrace_kernel<<<129, 64, 0, stream>>>(scFT, scFP, histXT, histXP,
        endT, endP, numT, denT, numP, denP, out);
}